// Round 13
// baseline (160.965 us; speedup 1.0000x reference)
//
#include <hip/hip_runtime.h>
#include <math.h>

#define NN   6464      // total nodes
#define NPER 101
#define HD   128
#define HE   16
#define NE   652864    // 64*101*101
#define PERB 10201     // 101*101
#define EPSB 1e-5f
#define SLOPE 0.2f
#define L2E  1.44269504088896340736f
#define NO   384       // t|U|V concatenated output width
#define NCB  7         // ceil(101/16) dest-chunks per batch

typedef __attribute__((ext_vector_type(8))) short bf16x8;
typedef __attribute__((ext_vector_type(4))) float f32x4;

__device__ __forceinline__ unsigned bf16r(float x){
    unsigned u = __float_as_uint(x);
    return (u + 0x7FFFu + ((u >> 16) & 1u)) >> 16;     // round-nearest-even
}
__device__ __forceinline__ unsigned pack2(float lo, float hi){
    return bf16r(lo) | (bf16r(hi) << 16);
}

// partial sums of eai (no atomics): part[blk], part[256+blk]
__global__ __launch_bounds__(256) void k_reduce1(const float* __restrict__ eai, float* __restrict__ part){
    __shared__ float ls[256], ls2[256];
    float s = 0.f, s2 = 0.f;
    for (int i = blockIdx.x*256 + threadIdx.x; i < NE; i += 256*256){
        float v = eai[i]; s += v; s2 += v*v;
    }
    int tid = threadIdx.x;
    ls[tid] = s; ls2[tid] = s2; __syncthreads();
    for (int o = 128; o > 0; o >>= 1){
        if (tid < o){ ls[tid] += ls[tid+o]; ls2[tid] += ls2[tid+o]; }
        __syncthreads();
    }
    if (tid == 0){ part[blockIdx.x] = ls[0]; part[256 + blockIdx.x] = ls2[0]; }
}

// Fused comp+setup. Blocks r<128: build Wt (bf16, TRANSPOSED [l][n][k]) rows.
// r==128 blocks (one per l): reduce stats, write c1 and dv.
__global__ __launch_bounds__(128) void k_comp2(const float* __restrict__ part,
                     const float* __restrict__ few, const float* __restrict__ beg,
                     const float* __restrict__ beb, const float* __restrict__ attn_b,
                     const float* __restrict__ fc_w, const float* __restrict__ fc_b,
                     const float* __restrict__ attn_w,
                     unsigned short* __restrict__ Wt, float* __restrict__ c1, float* __restrict__ dv){
    int blk = blockIdx.x;
    int l = blk / 129, r = blk - l*129;
    int tid = threadIdx.x;
    const float* Wi = attn_w + (size_t)l*272*HD;
    const float* Wj = Wi + HD*HD;
    const float* Fr = (r < HD) ? (fc_w + (size_t)l*HD*HD + (size_t)r*HD) : (fc_b + l*HD);
    float ai = 0.f, aj = 0.f;
    for (int m = 0; m < HD; m++){
        float f = Fr[m];
        ai = fmaf(f, Wi[m*HD + tid], ai);
        aj = fmaf(f, Wj[m*HD + tid], aj);
    }
    if (r < HD){
        unsigned short* Wl = Wt + (size_t)l*NO*HD;
        Wl[(size_t)(      tid)*HD + r] = (unsigned short)bf16r(Fr[tid]);      // t: n=tid
        Wl[(size_t)(128 + tid)*HD + r] = (unsigned short)bf16r(ai * L2E);     // U
        Wl[(size_t)(256 + tid)*HD + r] = (unsigned short)bf16r(aj * L2E);     // V
    } else {
        __shared__ float red[128], red2[128];
        float s = 0.f, s2 = 0.f;
        for (int t = tid; t < 256; t += 128){ s += part[t]; s2 += part[256 + t]; }
        red[tid] = s; red2[tid] = s2; __syncthreads();
        for (int o = 64; o > 0; o >>= 1){
            if (tid < o){ red[tid] += red[tid+o]; red2[tid] += red2[tid+o]; }
            __syncthreads();
        }
        float mean = red[0] * (1.f/NE);
        float var  = red2[0] * (1.f/NE) - mean*mean;
        __shared__ float sA[HE], sB[HE];
        if (tid < HE){
            float w = few[tid];
            float a = w * rsqrtf(var*w*w + EPSB) * beg[tid];
            sA[tid] = a; sB[tid] = beb[tid] - mean*a;
        }
        __syncthreads();
        const float* W = attn_w + ((size_t)l*272 + 256)*HD;
        float a1 = 0.f, a2 = 0.f;
        for (int k = 0; k < HE; k++){
            float wv = W[k*HD + tid];
            a1 += sA[k]*wv; a2 += sB[k]*wv;
        }
        c1[l*HD + tid] = a1 * L2E;
        dv[l*HD + tid] = (a2 + attn_b[l*HD + tid] + ai + aj) * L2E;
    }
}

// h0 = [x,demand] @ fc_node_w + b, training-mode BatchNorm over all N rows.
__global__ __launch_bounds__(256) void k_node_bn(const float* __restrict__ x, const float* __restrict__ demand,
                          const float* __restrict__ w, const float* __restrict__ b,
                          const float* __restrict__ g, const float* __restrict__ beta,
                          float* __restrict__ hbuf){
    int k = blockIdx.x, tid = threadIdx.x;
    float w0 = w[k], w1 = w[HD+k], w2 = w[2*HD+k], bb = b[k];
    float s = 0.f, s2 = 0.f;
    for (int n = tid; n < NN; n += 256){
        float p = x[2*n]*w0 + x[2*n+1]*w1 + demand[n]*w2 + bb;
        s += p; s2 += p*p;
    }
    __shared__ float ls[256], ls2[256];
    ls[tid] = s; ls2[tid] = s2; __syncthreads();
    for (int o = 128; o > 0; o >>= 1){
        if (tid < o){ ls[tid] += ls[tid+o]; ls2[tid] += ls2[tid+o]; }
        __syncthreads();
    }
    __shared__ float smu, srs;
    if (tid == 0){
        float mu = ls[0]*(1.f/NN);
        float var = ls2[0]*(1.f/NN) - mu*mu;
        smu = mu; srs = rsqrtf(var + EPSB);
    }
    __syncthreads();
    float mu = smu, rs = srs, gg = g[k], be = beta[k];
    for (int n = tid; n < NN; n += 256){
        float p = x[2*n]*w0 + x[2*n+1]*w1 + demand[n]*w2 + bb;
        hbuf[n*HD + k] = (p - mu)*rs*gg + be;
    }
}

// Transpose eai into esT[b][cb][j][slot] = eai[b, j, cb*16+slot] (16-wide chunks).
// Unfilled slots (i>100) stay poison -> read only by discarded lanes.
__global__ __launch_bounds__(256) void k_prep_es(const float* __restrict__ eai, float* __restrict__ esT){
    int b = blockIdx.x;
    const float* src = eai + (size_t)b*PERB;
    float* dst = esT + (size_t)b*NCB*NPER*16;
    for (int ji = threadIdx.x; ji < PERB; ji += 256){
        int j = (int)(((unsigned)ji * 10382u) >> 20);   // ji/101 exact for ji<=10200
        int i = ji - j*NPER;
        dst[(((size_t)(i >> 4))*NPER + j)*16 + (i & 15)] = src[ji];
    }
}

// MFMA GEMM: C[6464][384] = hbuf(bf16) @ Wt_l^T. 128x128 tile, 8 waves,
// each wave 2x4 fragments of 16x16x32_bf16, K=128 fully LDS-resident.
// bn==1 -> U as f32 into TUV(+128); bn==0/2 -> bf16-packed into TV16.
#define LDA 136
#define LDC 132
__global__ __launch_bounds__(512) void k_gemm16(const float* __restrict__ hbuf,
                     const unsigned short* __restrict__ Wt, const float* __restrict__ fc_b,
                     float* __restrict__ TUV, unsigned* __restrict__ TV16, int l){
    __shared__ short smem[2*128*LDA];      // As[128][136] | Bt[128][136] (69632 B)
    short* As = smem;
    short* Bt = smem + 128*LDA;
    float* Cs = (float*)smem;              // [128][132] f32 after barrier

    int bi = blockIdx.x;
    int bm = bi / 3, bn = bi - bm*3;
    int m0 = bm*128, n0g = bn*128;
    int tid = threadIdx.x;

    for (int idx = tid; idx < 128*32; idx += 512){
        int r = idx >> 5, k4 = (idx & 31) * 4;
        int row = m0 + r; if (row > NN-1) row = NN-1;
        float4 v = *(const float4*)&hbuf[(size_t)row*HD + k4];
        ushort4 w4;
        w4.x = (unsigned short)bf16r(v.x); w4.y = (unsigned short)bf16r(v.y);
        w4.z = (unsigned short)bf16r(v.z); w4.w = (unsigned short)bf16r(v.w);
        *(ushort4*)&As[r*LDA + k4] = w4;
    }
    const unsigned short* Wl = Wt + ((size_t)l*NO + n0g)*HD;
    for (int idx = tid; idx < 128*16; idx += 512){
        int n = idx >> 4, c = (idx & 15) * 8;
        *(uint4*)&Bt[n*LDA + c] = *(const uint4*)&Wl[(size_t)n*HD + c];
    }
    __syncthreads();

    int lane = tid & 63, w = tid >> 6;
    int mb = 32*(w & 3), nb = 64*(w >> 2);
    int lm = lane & 15, kg = lane >> 4;
    f32x4 acc[2][4];
    #pragma unroll
    for (int fm = 0; fm < 2; fm++)
        #pragma unroll
        for (int fn = 0; fn < 4; fn++) acc[fm][fn] = (f32x4){0.f,0.f,0.f,0.f};

    #pragma unroll
    for (int kk = 0; kk < 4; kk++){
        int ko = 32*kk + 8*kg;
        bf16x8 a0 = *(bf16x8*)&As[(mb      + lm)*LDA + ko];
        bf16x8 a1 = *(bf16x8*)&As[(mb + 16 + lm)*LDA + ko];
        bf16x8 b0 = *(bf16x8*)&Bt[(nb      + lm)*LDA + ko];
        bf16x8 b1 = *(bf16x8*)&Bt[(nb + 16 + lm)*LDA + ko];
        bf16x8 b2 = *(bf16x8*)&Bt[(nb + 32 + lm)*LDA + ko];
        bf16x8 b3 = *(bf16x8*)&Bt[(nb + 48 + lm)*LDA + ko];
        acc[0][0] = __builtin_amdgcn_mfma_f32_16x16x32_bf16(a0, b0, acc[0][0], 0,0,0);
        acc[0][1] = __builtin_amdgcn_mfma_f32_16x16x32_bf16(a0, b1, acc[0][1], 0,0,0);
        acc[0][2] = __builtin_amdgcn_mfma_f32_16x16x32_bf16(a0, b2, acc[0][2], 0,0,0);
        acc[0][3] = __builtin_amdgcn_mfma_f32_16x16x32_bf16(a0, b3, acc[0][3], 0,0,0);
        acc[1][0] = __builtin_amdgcn_mfma_f32_16x16x32_bf16(a1, b0, acc[1][0], 0,0,0);
        acc[1][1] = __builtin_amdgcn_mfma_f32_16x16x32_bf16(a1, b1, acc[1][1], 0,0,0);
        acc[1][2] = __builtin_amdgcn_mfma_f32_16x16x32_bf16(a1, b2, acc[1][2], 0,0,0);
        acc[1][3] = __builtin_amdgcn_mfma_f32_16x16x32_bf16(a1, b3, acc[1][3], 0,0,0);
    }
    __syncthreads();

    #pragma unroll
    for (int fm = 0; fm < 2; fm++)
        #pragma unroll
        for (int fn = 0; fn < 4; fn++)
            #pragma unroll
            for (int r = 0; r < 4; r++)
                Cs[(mb + 16*fm + 4*kg + r)*LDC + nb + 16*fn + lm] = acc[fm][fn][r];
    __syncthreads();

    if (bn == 1){
        for (int idx = tid; idx < 128*32; idx += 512){
            int r = idx >> 5, c4 = (idx & 31)*4;
            if (m0 + r < NN){
                float4 v = *(float4*)&Cs[r*LDC + c4];
                *(float4*)&TUV[(size_t)(m0+r)*NO + 128 + c4] = v;
            }
        }
    } else {
        int off = (bn == 2) ? 1 : 0;
        const float* fb = fc_b + l*HD;
        for (int idx = tid; idx < 128*64; idx += 512){
            int r = idx >> 6, p = idx & 63;
            if (m0 + r < NN){
                float lo = Cs[r*LDC + 2*p], hi = Cs[r*LDC + 2*p + 1];
                if (bn == 0){ lo += fb[2*p]; hi += fb[2*p+1]; }
                TV16[(size_t)(m0+r)*128 + 2*p + off] = pack2(lo, hi);
            }
        }
    }
}

// Attention v12: block = 16 dest nodes of one batch (7 blocks/batch, 448 blocks).
// 8 waves; wave w owns dest i0+2w, i0+2w+1 across ALL 128 channels (2/lane) and
// loops ALL 101 j itself — no j-split, no partial combine, no second barrier.
// t/V slab read ONCE per block (23 MB/layer, 3.7x less than v11); es broadcast
// from 6.5 KB LDS. blk = cb*64 + b keeps a batch's 7 blocks on one XCD (b%8).
__global__ __launch_bounds__(512) void k_attn12(const float* __restrict__ TUV,
                      const unsigned* __restrict__ TV16, const float* __restrict__ esT,
                      const float* __restrict__ c1, const float* __restrict__ dv,
                      float* __restrict__ hbuf, int l, float* __restrict__ outp){
    __shared__ float es_s[NPER][16];
    int blk = blockIdx.x;
    int b = blk & 63, cb = blk >> 6;       // cb in [0,7)
    int i0 = cb*16;
    int tid = threadIdx.x;
    int q = tid & 63, w = tid >> 6;
    int h0 = 2*q;

    // stage es chunk (contiguous 1616 floats; poison slots only feed discarded lanes)
    const float* ep = esT + ((size_t)(b*NCB + cb)*NPER)*16;
    for (int idx = tid; idx < NPER*16; idx += 512)
        ((float*)es_s)[idx] = ep[idx];

    int ia = i0 + 2*w, ib = i0 + 2*w + 1;
    int ca = (ia > NPER-1) ? NPER-1 : ia;  // clamped reads; stores guarded
    int cc = (ib > NPER-1) ? NPER-1 : ib;
    float2 c1h = *(const float2*)&c1[l*HD + h0];
    float2 dd  = *(const float2*)&dv[l*HD + h0];
    float2 uA  = *(const float2*)&TUV[(size_t)(b*NPER + ca)*NO + HD + h0];
    float2 uB  = *(const float2*)&TUV[(size_t)(b*NPER + cc)*NO + HD + h0];
    float bax = uA.x + dd.x, bay = uA.y + dd.y;
    float bbx = uB.x + dd.x, bby = uB.y + dd.y;
    float sax = 0.f, say = 0.f, aax = 0.f, aay = 0.f;
    float sbx = 0.f, sby = 0.f, abx = 0.f, aby = 0.f;
    __syncthreads();

    const unsigned* tvp = TV16 + (size_t)(b*NPER)*128 + h0;
    const float2* esw = (const float2*)&es_s[0][0] + w;   // row stride 8 float2
    uint2 A = *(const uint2*)tvp;
    float2 e = *esw;
    #pragma unroll 4
    for (int j = 0; j < NPER-1; j++){
        uint2 An = *(const uint2*)(tvp + 128);
        float2 en = esw[8];
        float tx = __uint_as_float(A.x << 16);
        float ty = __uint_as_float(A.x & 0xFFFF0000u);
        float vx = __uint_as_float(A.y << 16);
        float vy = __uint_as_float(A.y & 0xFFFF0000u);
        float zax = fmaf(e.x, c1h.x, bax + vx);
        float zay = fmaf(e.x, c1h.y, bay + vy);
        float zbx = fmaf(e.y, c1h.x, bbx + vx);
        float zby = fmaf(e.y, c1h.y, bby + vy);
        zax = fmaxf(zax, SLOPE*zax); zay = fmaxf(zay, SLOPE*zay);
        zbx = fmaxf(zbx, SLOPE*zbx); zby = fmaxf(zby, SLOPE*zby);
        float wax = __builtin_amdgcn_exp2f(zax);
        float way = __builtin_amdgcn_exp2f(zay);
        float wbx = __builtin_amdgcn_exp2f(zbx);
        float wby = __builtin_amdgcn_exp2f(zby);
        sax += wax; say += way; sbx += wbx; sby += wby;
        aax = fmaf(wax, tx, aax); aay = fmaf(way, ty, aay);
        abx = fmaf(wbx, tx, abx); aby = fmaf(wby, ty, aby);
        tvp += 128; esw += 8;
        A = An; e = en;
    }
    {   // peeled j = 100
        float tx = __uint_as_float(A.x << 16);
        float ty = __uint_as_float(A.x & 0xFFFF0000u);
        float vx = __uint_as_float(A.y << 16);
        float vy = __uint_as_float(A.y & 0xFFFF0000u);
        float zax = fmaf(e.x, c1h.x, bax + vx);
        float zay = fmaf(e.x, c1h.y, bay + vy);
        float zbx = fmaf(e.y, c1h.x, bbx + vx);
        float zby = fmaf(e.y, c1h.y, bby + vy);
        zax = fmaxf(zax, SLOPE*zax); zay = fmaxf(zay, SLOPE*zay);
        zbx = fmaxf(zbx, SLOPE*zbx); zby = fmaxf(zby, SLOPE*zby);
        float wax = __builtin_amdgcn_exp2f(zax);
        float way = __builtin_amdgcn_exp2f(zay);
        float wbx = __builtin_amdgcn_exp2f(zbx);
        float wby = __builtin_amdgcn_exp2f(zby);
        sax += wax; say += way; sbx += wbx; sby += wby;
        aax = fmaf(wax, tx, aax); aay = fmaf(way, ty, aay);
        abx = fmaf(wbx, tx, abx); aby = fmaf(wby, ty, aby);
    }

    if (ia < NPER){
        size_t o = (size_t)(b*NPER + ia)*HD + h0;
        float2 hres = *(const float2*)&hbuf[o];
        hres.x = fmaf(aax, __builtin_amdgcn_rcpf(sax + 1e-16f), hres.x);
        hres.y = fmaf(aay, __builtin_amdgcn_rcpf(say + 1e-16f), hres.y);
        *(float2*)&hbuf[o] = hres;
        if (outp) *(float2*)&outp[o] = hres;
    }
    if (ib < NPER){
        size_t o = (size_t)(b*NPER + ib)*HD + h0;
        float2 hres = *(const float2*)&hbuf[o];
        hres.x = fmaf(abx, __builtin_amdgcn_rcpf(sbx + 1e-16f), hres.x);
        hres.y = fmaf(aby, __builtin_amdgcn_rcpf(sby + 1e-16f), hres.y);
        *(float2*)&hbuf[o] = hres;
        if (outp) *(float2*)&outp[o] = hres;
    }
}

extern "C" void kernel_launch(void* const* d_in, const int* in_sizes, int n_in,
                              void* d_out, int out_size, void* d_ws, size_t ws_size,
                              hipStream_t stream) {
    const float* x      = (const float*)d_in[0];
    const float* demand = (const float*)d_in[1];
    const float* eai    = (const float*)d_in[2];
    // d_in[3] edge_index: known constant structure, unused
    const float* fnw = (const float*)d_in[4];
    const float* fnb = (const float*)d_in[5];
    const float* bng = (const float*)d_in[6];
    const float* bnb = (const float*)d_in[7];
    const float* few = (const float*)d_in[8];
    // d_in[9] fc_edge_b cancels in BatchNorm
    const float* beg = (const float*)d_in[10];
    const float* beb = (const float*)d_in[11];
    const float* fcw = (const float*)d_in[12];
    const float* fcb = (const float*)d_in[13];
    const float* aw  = (const float*)d_in[14];
    const float* ab  = (const float*)d_in[15];
    float* out = (float*)d_out;

    float* w     = (float*)d_ws;
    float* hbuf  = w;                            // NN*128 f32
    float* TUV   = w + (size_t)NN*HD;            // NN*384 f32 (only U-slice used)
    unsigned* TV16 = (unsigned*)(TUV + (size_t)NN*NO);   // NN*128 u32
    float* esT   = (float*)(TV16 + (size_t)NN*128);      // 64*7*101*16
    float* part  = esT + (size_t)64*NCB*NPER*16; // 512
    float* c1    = part + 512;                   // 3*128
    float* dv    = c1 + 3*HD;                    // 3*128
    unsigned short* Wt = (unsigned short*)(dv + 3*HD);   // 3*384*128 bf16

    hipLaunchKernelGGL(k_reduce1, dim3(256), dim3(256), 0, stream, eai, part);
    hipLaunchKernelGGL(k_comp2, dim3(3*129), dim3(HD), 0, stream,
                       part, few, beg, beb, ab, fcw, fcb, aw, Wt, c1, dv);
    hipLaunchKernelGGL(k_node_bn, dim3(HD), dim3(256), 0, stream, x, demand, fnw, fnb, bng, bnb, hbuf);
    hipLaunchKernelGGL(k_prep_es, dim3(64), dim3(256), 0, stream, eai, esT);
    for (int l = 0; l < 3; l++){
        hipLaunchKernelGGL(k_gemm16, dim3(51*3), dim3(512), 0, stream,
                           hbuf, Wt, fcb, TUV, TV16, l);
        hipLaunchKernelGGL(k_attn12, dim3(64*NCB), dim3(512), 0, stream,
                           TUV, TV16, esT, c1, dv, hbuf, l, (l == 2) ? out : (float*)nullptr);
    }
}

// Round 14
// 150.854 us; speedup vs baseline: 1.0670x; 1.0670x over previous
//
#include <hip/hip_runtime.h>
#include <math.h>

#define NN   6464      // total nodes
#define NPER 101
#define HD   128
#define HE   16
#define NE   652864    // 64*101*101
#define PERB 10201     // 101*101
#define EPSB 1e-5f
#define SLOPE 0.2f
#define TI   4         // dest nodes per attention block
#define NBLK 26        // ceil(101/4)
#define L2E  1.44269504088896340736f
#define NO   384       // t|U|V concatenated output width

typedef __attribute__((ext_vector_type(8))) short bf16x8;
typedef __attribute__((ext_vector_type(4))) float f32x4;
typedef __attribute__((ext_vector_type(2))) float f32x2;

__device__ __forceinline__ unsigned bf16r(float x){
    unsigned u = __float_as_uint(x);
    return (u + 0x7FFFu + ((u >> 16) & 1u)) >> 16;     // round-nearest-even
}
__device__ __forceinline__ unsigned pack2(float lo, float hi){
    return bf16r(lo) | (bf16r(hi) << 16);
}

// Fused: transpose eai into esT[b][c][j][k] = eai[b, j, c*4+k] AND produce
// per-batch partial sums part[b], part[64+b] for the edge BatchNorm stats.
__global__ __launch_bounds__(256) void k_prep_es(const float* __restrict__ eai, float* __restrict__ esT,
                         float* __restrict__ part){
    __shared__ float ls[256], ls2[256];
    int b = blockIdx.x;
    const float* src = eai + (size_t)b*PERB;
    float* dst = esT + (size_t)b*NBLK*NPER*4;
    float s = 0.f, s2 = 0.f;
    for (int ji = threadIdx.x; ji < PERB; ji += 256){
        int j = (int)(((unsigned)ji * 10382u) >> 20);   // ji/101 exact for ji<=10200
        int i = ji - j*NPER;
        float v = src[ji];
        s += v; s2 += v*v;
        dst[(((size_t)(i >> 2))*NPER + j)*4 + (i & 3)] = v;
    }
    int tid = threadIdx.x;
    ls[tid] = s; ls2[tid] = s2; __syncthreads();
    for (int o = 128; o > 0; o >>= 1){
        if (tid < o){ ls[tid] += ls[tid+o]; ls2[tid] += ls2[tid+o]; }
        __syncthreads();
    }
    if (tid == 0){ part[b] = ls[0]; part[64 + b] = ls2[0]; }
}

// Fused comp+setup. Blocks r<128: build Wt (bf16, TRANSPOSED [l][n][k]) rows.
// r==128 blocks (one per l): reduce stats, write c1 and dv.
__global__ __launch_bounds__(128) void k_comp2(const float* __restrict__ part,
                     const float* __restrict__ few, const float* __restrict__ beg,
                     const float* __restrict__ beb, const float* __restrict__ attn_b,
                     const float* __restrict__ fc_w, const float* __restrict__ fc_b,
                     const float* __restrict__ attn_w,
                     unsigned short* __restrict__ Wt, float* __restrict__ c1, float* __restrict__ dv){
    int blk = blockIdx.x;
    int l = blk / 129, r = blk - l*129;
    int tid = threadIdx.x;
    const float* Wi = attn_w + (size_t)l*272*HD;
    const float* Wj = Wi + HD*HD;
    const float* Fr = (r < HD) ? (fc_w + (size_t)l*HD*HD + (size_t)r*HD) : (fc_b + l*HD);
    float ai = 0.f, aj = 0.f;
    for (int m = 0; m < HD; m++){
        float f = Fr[m];
        ai = fmaf(f, Wi[m*HD + tid], ai);
        aj = fmaf(f, Wj[m*HD + tid], aj);
    }
    if (r < HD){
        unsigned short* Wl = Wt + (size_t)l*NO*HD;
        Wl[(size_t)(      tid)*HD + r] = (unsigned short)bf16r(Fr[tid]);      // t: n=tid
        Wl[(size_t)(128 + tid)*HD + r] = (unsigned short)bf16r(ai * L2E);     // U
        Wl[(size_t)(256 + tid)*HD + r] = (unsigned short)bf16r(aj * L2E);     // V
    } else {
        __shared__ float red[128], red2[128];
        float s = (tid < 64) ? part[tid] : 0.f;
        float s2 = (tid < 64) ? part[64 + tid] : 0.f;
        red[tid] = s; red2[tid] = s2; __syncthreads();
        for (int o = 64; o > 0; o >>= 1){
            if (tid < o){ red[tid] += red[tid+o]; red2[tid] += red2[tid+o]; }
            __syncthreads();
        }
        float mean = red[0] * (1.f/NE);
        float var  = red2[0] * (1.f/NE) - mean*mean;
        __shared__ float sA[HE], sB[HE];
        if (tid < HE){
            float w = few[tid];
            float a = w * rsqrtf(var*w*w + EPSB) * beg[tid];
            sA[tid] = a; sB[tid] = beb[tid] - mean*a;
        }
        __syncthreads();
        const float* W = attn_w + ((size_t)l*272 + 256)*HD;
        float a1 = 0.f, a2 = 0.f;
        for (int k = 0; k < HE; k++){
            float wv = W[k*HD + tid];
            a1 += sA[k]*wv; a2 += sB[k]*wv;
        }
        c1[l*HD + tid] = a1 * L2E;
        dv[l*HD + tid] = (a2 + attn_b[l*HD + tid] + ai + aj) * L2E;
    }
}

// h0 = [x,demand] @ fc_node_w + b, training-mode BatchNorm over all N rows.
__global__ __launch_bounds__(256) void k_node_bn(const float* __restrict__ x, const float* __restrict__ demand,
                          const float* __restrict__ w, const float* __restrict__ b,
                          const float* __restrict__ g, const float* __restrict__ beta,
                          float* __restrict__ hbuf){
    int k = blockIdx.x, tid = threadIdx.x;
    float w0 = w[k], w1 = w[HD+k], w2 = w[2*HD+k], bb = b[k];
    float s = 0.f, s2 = 0.f;
    for (int n = tid; n < NN; n += 256){
        float p = x[2*n]*w0 + x[2*n+1]*w1 + demand[n]*w2 + bb;
        s += p; s2 += p*p;
    }
    __shared__ float ls[256], ls2[256];
    ls[tid] = s; ls2[tid] = s2; __syncthreads();
    for (int o = 128; o > 0; o >>= 1){
        if (tid < o){ ls[tid] += ls[tid+o]; ls2[tid] += ls2[tid+o]; }
        __syncthreads();
    }
    __shared__ float smu, srs;
    if (tid == 0){
        float mu = ls[0]*(1.f/NN);
        float var = ls2[0]*(1.f/NN) - mu*mu;
        smu = mu; srs = rsqrtf(var + EPSB);
    }
    __syncthreads();
    float mu = smu, rs = srs, gg = g[k], be = beta[k];
    for (int n = tid; n < NN; n += 256){
        float p = x[2*n]*w0 + x[2*n+1]*w1 + demand[n]*w2 + bb;
        hbuf[n*HD + k] = (p - mu)*rs*gg + be;
    }
}

// MFMA GEMM: C[6464][384] = hbuf(bf16) @ Wt_l^T. 128x128 tile, 8 waves,
// each wave 2x4 fragments of 16x16x32_bf16, K=128 fully LDS-resident.
// bn==1 -> U as f32 into TUV(+128); bn==0/2 -> bf16-packed into TV16.
#define LDA 136
#define LDC 132
__global__ __launch_bounds__(512) void k_gemm16(const float* __restrict__ hbuf,
                     const unsigned short* __restrict__ Wt, const float* __restrict__ fc_b,
                     float* __restrict__ TUV, unsigned* __restrict__ TV16, int l){
    __shared__ short smem[2*128*LDA];      // As[128][136] | Bt[128][136] (69632 B)
    short* As = smem;
    short* Bt = smem + 128*LDA;
    float* Cs = (float*)smem;              // [128][132] f32 after barrier

    int bi = blockIdx.x;
    int bm = bi / 3, bn = bi - bm*3;
    int m0 = bm*128, n0g = bn*128;
    int tid = threadIdx.x;

    for (int idx = tid; idx < 128*32; idx += 512){
        int r = idx >> 5, k4 = (idx & 31) * 4;
        int row = m0 + r; if (row > NN-1) row = NN-1;
        float4 v = *(const float4*)&hbuf[(size_t)row*HD + k4];
        ushort4 w4;
        w4.x = (unsigned short)bf16r(v.x); w4.y = (unsigned short)bf16r(v.y);
        w4.z = (unsigned short)bf16r(v.z); w4.w = (unsigned short)bf16r(v.w);
        *(ushort4*)&As[r*LDA + k4] = w4;
    }
    const unsigned short* Wl = Wt + ((size_t)l*NO + n0g)*HD;
    for (int idx = tid; idx < 128*16; idx += 512){
        int n = idx >> 4, c = (idx & 15) * 8;
        *(uint4*)&Bt[n*LDA + c] = *(const uint4*)&Wl[(size_t)n*HD + c];
    }
    __syncthreads();

    int lane = tid & 63, w = tid >> 6;
    int mb = 32*(w & 3), nb = 64*(w >> 2);
    int lm = lane & 15, kg = lane >> 4;
    f32x4 acc[2][4];
    #pragma unroll
    for (int fm = 0; fm < 2; fm++)
        #pragma unroll
        for (int fn = 0; fn < 4; fn++) acc[fm][fn] = (f32x4){0.f,0.f,0.f,0.f};

    #pragma unroll
    for (int kk = 0; kk < 4; kk++){
        int ko = 32*kk + 8*kg;
        bf16x8 a0 = *(bf16x8*)&As[(mb      + lm)*LDA + ko];
        bf16x8 a1 = *(bf16x8*)&As[(mb + 16 + lm)*LDA + ko];
        bf16x8 b0 = *(bf16x8*)&Bt[(nb      + lm)*LDA + ko];
        bf16x8 b1 = *(bf16x8*)&Bt[(nb + 16 + lm)*LDA + ko];
        bf16x8 b2 = *(bf16x8*)&Bt[(nb + 32 + lm)*LDA + ko];
        bf16x8 b3 = *(bf16x8*)&Bt[(nb + 48 + lm)*LDA + ko];
        acc[0][0] = __builtin_amdgcn_mfma_f32_16x16x32_bf16(a0, b0, acc[0][0], 0,0,0);
        acc[0][1] = __builtin_amdgcn_mfma_f32_16x16x32_bf16(a0, b1, acc[0][1], 0,0,0);
        acc[0][2] = __builtin_amdgcn_mfma_f32_16x16x32_bf16(a0, b2, acc[0][2], 0,0,0);
        acc[0][3] = __builtin_amdgcn_mfma_f32_16x16x32_bf16(a0, b3, acc[0][3], 0,0,0);
        acc[1][0] = __builtin_amdgcn_mfma_f32_16x16x32_bf16(a1, b0, acc[1][0], 0,0,0);
        acc[1][1] = __builtin_amdgcn_mfma_f32_16x16x32_bf16(a1, b1, acc[1][1], 0,0,0);
        acc[1][2] = __builtin_amdgcn_mfma_f32_16x16x32_bf16(a1, b2, acc[1][2], 0,0,0);
        acc[1][3] = __builtin_amdgcn_mfma_f32_16x16x32_bf16(a1, b3, acc[1][3], 0,0,0);
    }
    __syncthreads();

    #pragma unroll
    for (int fm = 0; fm < 2; fm++)
        #pragma unroll
        for (int fn = 0; fn < 4; fn++)
            #pragma unroll
            for (int r = 0; r < 4; r++)
                Cs[(mb + 16*fm + 4*kg + r)*LDC + nb + 16*fn + lm] = acc[fm][fn][r];
    __syncthreads();

    if (bn == 1){
        for (int idx = tid; idx < 128*32; idx += 512){
            int r = idx >> 5, c4 = (idx & 31)*4;
            if (m0 + r < NN){
                float4 v = *(float4*)&Cs[r*LDC + c4];
                *(float4*)&TUV[(size_t)(m0+r)*NO + 128 + c4] = v;
            }
        }
    } else {
        int off = (bn == 2) ? 1 : 0;
        const float* fb = fc_b + l*HD;
        for (int idx = tid; idx < 128*64; idx += 512){
            int r = idx >> 6, p = idx & 63;
            if (m0 + r < NN){
                float lo = Cs[r*LDC + 2*p], hi = Cs[r*LDC + 2*p + 1];
                if (bn == 0){ lo += fb[2*p]; hi += fb[2*p+1]; }
                TV16[(size_t)(m0+r)*128 + 2*p + off] = pack2(lo, hi);
            }
        }
    }
}

// Attention core: CNT rows, compile-time indices; ONE uint2 load per j carries
// bf16 {t-pair, V-pair}. Channel-pair math in f32x2 ext-vectors so the backend
// emits packed v_pk_fma_f32 / v_pk_max_f32 / v_pk_add_f32 (VALU ~44 -> ~28 per j).
template<int CNT>
__device__ __forceinline__ void attn_core(const unsigned* tvp, const float4* esp,
                                          f32x2 c1h, const f32x2* base,
                                          f32x2* s, f32x2* acc){
    constexpr int NCH = (CNT + 3) / 4;
    uint2 A[4], B[4];
    #pragma unroll
    for (int r = 0; r < 4; ++r)
        if (r < CNT) A[r] = *(const uint2*)(tvp + r*128);
    #pragma unroll
    for (int ch = 0; ch < NCH; ++ch){
        const int jb = ch*4;
        #pragma unroll
        for (int r = 0; r < 4; ++r){
            const int jn = jb + 4 + r;
            if (jn < CNT) B[r] = *(const uint2*)(tvp + jn*128);
        }
        #pragma unroll
        for (int r = 0; r < 4; ++r){
            const int j = jb + r;
            if (j < CNT){
                const float4 e4 = esp[j];
                const float ev[4] = {e4.x, e4.y, e4.z, e4.w};
                f32x2 t2, v2;
                t2.x = __uint_as_float(A[r].x << 16);
                t2.y = __uint_as_float(A[r].x & 0xFFFF0000u);
                v2.x = __uint_as_float(A[r].y << 16);
                v2.y = __uint_as_float(A[r].y & 0xFFFF0000u);
                #pragma unroll
                for (int k = 0; k < TI; ++k){
                    f32x2 z = ev[k]*c1h + (base[k] + v2);          // v_pk_add + v_pk_fma
                    z = __builtin_elementwise_max(z, z*SLOPE);     // v_pk_mul + v_pk_max
                    f32x2 wv;
                    wv.x = __builtin_amdgcn_exp2f(z.x);
                    wv.y = __builtin_amdgcn_exp2f(z.y);
                    s[k] += wv;                                    // v_pk_add
                    acc[k] += wv * t2;                             // v_pk_fma
                }
            }
        }
        #pragma unroll
        for (int r = 0; r < 4; ++r) A[r] = B[r];
    }
}

// Attention v11p: TI=4, 8 waves own 13/10 j-rows; bf16-packed TV loads; pk-f32 math.
__global__ __launch_bounds__(512) void k_attn11(const float* __restrict__ TUV,
                      const unsigned* __restrict__ TV16, const float* __restrict__ esT,
                      const float* __restrict__ c1, const float* __restrict__ dv,
                      float* __restrict__ hbuf, int l, float* __restrict__ outp){
    __shared__ float4 es4[NPER];
    __shared__ float ps[8][TI][HD], pa[8][TI][HD];
    int blk = blockIdx.x;
    int xcd = blk & 7, r = blk >> 3;       // XCD-aware swizzle (bijective: 1664 = 8*208)
    int b = xcd + 8*(r & 7), c = r >> 3;
    int i0 = c*TI;
    int tid = threadIdx.x;
    int q = tid & 63, jg = tid >> 6;
    int h0 = 2*q;

    const float* ep = esT + ((size_t)(b*NBLK + c)*NPER)*4;
    for (int idx = tid; idx < NPER*4; idx += 512)
        ((float*)es4)[idx] = ep[idx];

    f32x2 c1h = *(const f32x2*)&c1[l*HD + h0];
    f32x2 dd  = *(const f32x2*)&dv[l*HD + h0];
    f32x2 base[TI], s[TI], acc[TI];
    #pragma unroll
    for (int k = 0; k < TI; k++){
        int i = i0 + k; if (i > NPER-1) i = NPER-1;
        f32x2 uu = *(const f32x2*)&TUV[(size_t)(b*NPER + i)*NO + HD + h0];
        base[k] = uu + dd;
        s[k] = (f32x2){0.f, 0.f}; acc[k] = (f32x2){0.f, 0.f};
    }
    __syncthreads();

    const unsigned* tvp = TV16 + (size_t)(b*NPER + jg*13)*128 + 2*q;
    const float4* esp = es4 + jg*13;
    if (jg < 7) attn_core<13>(tvp, esp, c1h, base, s, acc);
    else        attn_core<10>(tvp, esp, c1h, base, s, acc);

    #pragma unroll
    for (int k = 0; k < TI; k++){
        *(f32x2*)&ps[jg][k][h0] = s[k];
        *(f32x2*)&pa[jg][k][h0] = acc[k];
    }
    __syncthreads();
    {
        int k = tid >> 7, h = tid & (HD-1);
        int i = i0 + k;
        if (i < NPER){
            float st = 0.f, at = 0.f;
            #pragma unroll
            for (int g = 0; g < 8; g++){ st += ps[g][k][h]; at += pa[g][k][h]; }
            size_t o = (size_t)(b*NPER + i)*HD + h;
            float res = fmaf(at, __builtin_amdgcn_rcpf(st + 1e-16f), hbuf[o]);
            hbuf[o] = res;
            if (outp) outp[o] = res;
        }
    }
}

extern "C" void kernel_launch(void* const* d_in, const int* in_sizes, int n_in,
                              void* d_out, int out_size, void* d_ws, size_t ws_size,
                              hipStream_t stream) {
    const float* x      = (const float*)d_in[0];
    const float* demand = (const float*)d_in[1];
    const float* eai    = (const float*)d_in[2];
    // d_in[3] edge_index: known constant structure, unused
    const float* fnw = (const float*)d_in[4];
    const float* fnb = (const float*)d_in[5];
    const float* bng = (const float*)d_in[6];
    const float* bnb = (const float*)d_in[7];
    const float* few = (const float*)d_in[8];
    // d_in[9] fc_edge_b cancels in BatchNorm
    const float* beg = (const float*)d_in[10];
    const float* beb = (const float*)d_in[11];
    const float* fcw = (const float*)d_in[12];
    const float* fcb = (const float*)d_in[13];
    const float* aw  = (const float*)d_in[14];
    const float* ab  = (const float*)d_in[15];
    float* out = (float*)d_out;

    float* w     = (float*)d_ws;
    float* hbuf  = w;                            // NN*128 f32
    float* TUV   = w + (size_t)NN*HD;            // NN*384 f32 (only U-slice used)
    unsigned* TV16 = (unsigned*)(TUV + (size_t)NN*NO);   // NN*128 u32
    float* esT   = (float*)(TV16 + (size_t)NN*128);      // 64*26*101*4
    float* part  = esT + (size_t)64*NBLK*NPER*4; // 128
    float* c1    = part + 128;                   // 3*128
    float* dv    = c1 + 3*HD;                    // 3*128
    unsigned short* Wt = (unsigned short*)(dv + 3*HD);   // 3*384*128 bf16

    hipLaunchKernelGGL(k_prep_es, dim3(64), dim3(256), 0, stream, eai, esT, part);
    hipLaunchKernelGGL(k_comp2, dim3(3*129), dim3(HD), 0, stream,
                       part, few, beg, beb, ab, fcw, fcb, aw, Wt, c1, dv);
    hipLaunchKernelGGL(k_node_bn, dim3(HD), dim3(256), 0, stream, x, demand, fnw, fnb, bng, bnb, hbuf);
    for (int l = 0; l < 3; l++){
        hipLaunchKernelGGL(k_gemm16, dim3(51*3), dim3(512), 0, stream,
                           hbuf, Wt, fcb, TUV, TV16, l);
        hipLaunchKernelGGL(k_attn11, dim3(64*NBLK), dim3(512), 0, stream,
                           TUV, TV16, esT, c1, dv, hbuf, l, (l == 2) ? out : (float*)nullptr);
    }
}